// Round 5
// baseline (966.999 us; speedup 1.0000x reference)
//
#include <hip/hip_runtime.h>

typedef unsigned short u16;
typedef unsigned int u32;

constexpr int NN = 100000;   // nodes
constexpr int NE = 1600000;  // edges
constexpr int H = 128;       // hidden

constexpr int NB = 196;      // coarse buckets: b = dst >> 9 (512 nodes/bucket)
constexpr int BCAP = 10240;  // per-bucket capacity (mean 8192, +22 sigma)
constexpr int PB_E = 4096;   // edges per partition block
constexpr int PB_BLOCKS = (NE + PB_E - 1) / PB_E;  // 391

typedef __bf16 bf16x8 __attribute__((ext_vector_type(8)));
typedef float f32x16 __attribute__((ext_vector_type(16)));

__device__ __forceinline__ u16 f2bf(float f) {
    union { float f; u32 u; } cv; cv.f = f;
    u32 r = (cv.u + 0x7fffu + ((cv.u >> 16) & 1u)) >> 16;
    return (u16)r;
}
__device__ __forceinline__ float bflo(u32 u) {
    union { u32 u; float f; } cv; cv.u = u << 16; return cv.f;
}
__device__ __forceinline__ float bfhi(u32 u) {
    union { u32 u; float f; } cv; cv.u = u & 0xffff0000u; return cv.f;
}

// ---- detect int64 vs int32 edge storage -------------------------------------
__global__ void detect_kernel(const int* __restrict__ e, int* __restrict__ flag,
                              int* __restrict__ gcursor) {
    __shared__ int anynz;
    if (threadIdx.x == 0) anynz = 0;
    __syncthreads();
    int local = 0;
    for (int i = threadIdx.x; i < 4096; i += 256)
        if (e[2 * i + 1] != 0) local = 1;
    if (local) atomicOr(&anynz, 1);
    __syncthreads();
    if (threadIdx.x == 0) flag[0] = anynz ? 1 : 2;  // stride in int32 units
    if (threadIdx.x < NB) gcursor[threadIdx.x] = 0;
}

// ---- partition edges into NB dst-buckets (packed src|ldst) -------------------
__global__ __launch_bounds__(256) void part_kernel(const int* __restrict__ e,
                                                   const int* __restrict__ flag,
                                                   int* __restrict__ gcursor,
                                                   u32* __restrict__ ebuf) {
    __shared__ int lcnt[NB];
    __shared__ int gbaseL[NB];
    const int t = threadIdx.x;
    if (t < NB) lcnt[t] = 0;
    __syncthreads();
    const int st = flag[0];
    const int base = blockIdx.x * PB_E;
    u32 pk[16]; int bk[16]; int rk[16];
#pragma unroll
    for (int j = 0; j < 16; ++j) {
        int i = base + j * 256 + t;
        bk[j] = -1;
        if (i < NE) {
            int s = e[st * i];
            int d = e[st * (NE + i)];
            int b = d >> 9;
            pk[j] = (u32)s | ((u32)(d & 511) << 17);
            bk[j] = b;
            rk[j] = atomicAdd(&lcnt[b], 1);
        }
    }
    __syncthreads();
    if (t < NB) gbaseL[t] = atomicAdd(&gcursor[t], lcnt[t]);
    __syncthreads();
#pragma unroll
    for (int j = 0; j < 16; ++j)
        if (bk[j] >= 0)
            ebuf[bk[j] * BCAP + gbaseL[bk[j]] + rk[j]] = pk[j];
}

// ---- exclusive scan of bucket totals ----------------------------------------
__global__ __launch_bounds__(256) void bscan_kernel(const int* __restrict__ gcursor,
                                                    int* __restrict__ bbase,
                                                    int* __restrict__ offs) {
    __shared__ int s[256];
    int t = threadIdx.x;
    int v = (t < NB) ? gcursor[t] : 0;
    s[t] = v;
    __syncthreads();
    for (int off = 1; off < 256; off <<= 1) {
        int u = (t >= off) ? s[t - off] : 0;
        __syncthreads();
        s[t] += u;
        __syncthreads();
    }
    if (t < NB) bbase[t] = s[t] - v;
    if (t == 0) offs[NN] = NE;
}

// ---- per-bucket CSR fill: LDS node counts/scan/cursors, local colv scatter ---
__global__ __launch_bounds__(256) void bfill_kernel(const u32* __restrict__ ebuf,
                                                    const int* __restrict__ gcursor,
                                                    const int* __restrict__ bbase,
                                                    int* __restrict__ offs,
                                                    int* __restrict__ colv) {
    __shared__ int ncnt[512];
    __shared__ int cur[512];
    __shared__ int ps[256];
    const int b = blockIdx.x, t = threadIdx.x;
    const int En = gcursor[b];
    const int bb = bbase[b];
    ncnt[t] = 0; ncnt[t + 256] = 0;
    __syncthreads();
    const u32* eb = ebuf + b * BCAP;
    for (int i = t; i < En; i += 256)
        atomicAdd(&ncnt[eb[i] >> 17], 1);
    __syncthreads();
    int s2 = ncnt[2 * t] + ncnt[2 * t + 1];
    ps[t] = s2;
    __syncthreads();
    for (int off = 1; off < 256; off <<= 1) {
        int u = (t >= off) ? ps[t - off] : 0;
        __syncthreads();
        ps[t] += u;
        __syncthreads();
    }
    int e0 = ps[t] - s2;  // exclusive
    cur[2 * t] = e0;
    cur[2 * t + 1] = e0 + ncnt[2 * t];
    __syncthreads();
    const int n0 = b * 512;
    for (int i = t; i < 512; i += 256)
        if (n0 + i < NN) offs[n0 + i] = bb + cur[i];
    __syncthreads();  // offs reads of cur[] complete before pass2 mutates
    for (int i = t; i < En; i += 256) {
        u32 p = eb[i];
        int pos = atomicAdd(&cur[p >> 17], 1);
        colv[bb + pos] = (int)(p & 0x1FFFFu);
    }
}

// ---- transpose+convert weights: Wt[l*2+s][n][k] = W[l][k][n] (bf16) ---------
__global__ void wtconv_kernel(const float* __restrict__ W1,
                              const float* __restrict__ W2,
                              u16* __restrict__ wt) {
    int t = blockIdx.x * 256 + threadIdx.x;  // 131072 threads
    int w = t >> 14;      // 0..7 = l*2+s
    int r = t & 16383;
    int k = r >> 7, n = r & 127;  // n fastest -> coalesced reads
    int l = w >> 1, s = w & 1;
    const float* src = (s == 0 ? W1 : W2) + l * 16384;
    wt[w * 16384 + n * 128 + k] = f2bf(src[k * 128 + n]);
}

// ---- x init: copy fp32 x -> d_out, make bf16 shadow -------------------------
__global__ void xinit_kernel(const float* __restrict__ xin,
                             float* __restrict__ x, u16* __restrict__ xb) {
    int i = blockIdx.x * 256 + threadIdx.x;  // NN*H/4 threads
    float4 v = ((const float4*)xin)[i];
    ((float4*)x)[i] = v;
    uint2 p;
    p.x = (u32)f2bf(v.x) | ((u32)f2bf(v.y) << 16);
    p.y = (u32)f2bf(v.z) | ((u32)f2bf(v.w) << 16);
    ((uint2*)xb)[i] = p;
}

// ---- fused layer: gather -> LDS A-tile -> MLP -> residual update ------------
// block = 128 nodes, 4 waves. Reads xbin (layer-l shadow), writes xbout
// (layer-l+1 shadow). Double-buffered across layers: no block reads a row
// any block writes within one dispatch (XCD non-coherence safe).
__global__ __launch_bounds__(256) void layer_kernel(const u16* __restrict__ xbin,
                                                    const int* __restrict__ colv,
                                                    const int* __restrict__ offs,
                                                    const u16* __restrict__ wt1,
                                                    const u16* __restrict__ wt2,
                                                    const float* __restrict__ b1,
                                                    const float* __restrict__ b2,
                                                    float* __restrict__ x,
                                                    u16* __restrict__ xbout) {
    __shared__ u16 lds[128 * 128];  // 32KB, XOR-swizzled 16B chunks
    const int tid = threadIdx.x;
    const int wave = tid >> 6, lane = tid & 63;
    const int wm = wave >> 1, wn = wave & 1;  // 2x2 wave grid for MFMA phase
    const int ml = lane & 31, g = lane >> 5;
    const int row0 = blockIdx.x * 128;

    // ---- phase 1: gather. wave w produces rows w*32 .. w*32+31 --------------
    u32* lds32 = (u32*)lds;
    for (int i = 0; i < 32; ++i) {
        const int r = wave * 32 + i;
        const int node = row0 + r;
        u32 o = 0;
        if (node < NN) {
            const int rs = offs[node], re = offs[node + 1];
            u32 su = *(const u32*)(xbin + node * H + lane * 2);
            float a0 = bflo(su), a1 = bfhi(su);
            for (int base = rs; base < re; base += 64) {
                int cnt = re - base; if (cnt > 64) cnt = 64;
                int c = 0;
                if (lane < cnt) c = colv[base + lane];
                int j = 0;
                for (; j + 8 <= cnt; j += 8) {
                    u32 uu[8];
#pragma unroll
                    for (int q = 0; q < 8; ++q) {
                        int s = __shfl(c, j + q);
                        uu[q] = *(const u32*)(xbin + s * H + lane * 2);
                    }
#pragma unroll
                    for (int q = 0; q < 8; ++q) { a0 += bflo(uu[q]); a1 += bfhi(uu[q]); }
                }
                for (; j < cnt; ++j) {
                    int s = __shfl(c, j);
                    u32 u = *(const u32*)(xbin + s * H + lane * 2);
                    a0 += bflo(u); a1 += bfhi(u);
                }
            }
            o = (u32)f2bf(a0) | ((u32)f2bf(a1) << 16);
        }
        // swizzled LDS write: row r, u32-slot lane (16B chunk = lane>>2)
        int chunk = (lane >> 2) ^ (r & 15);
        lds32[r * 64 + (chunk << 2) + (lane & 3)] = o;
    }

    // ---- B1 fragments from global (L2-resident) -----------------------------
    bf16x8 bfrag[2][8];
#pragma unroll
    for (int nt = 0; nt < 2; ++nt)
#pragma unroll
        for (int ks = 0; ks < 8; ++ks)
            bfrag[nt][ks] = *(const bf16x8*)(wt1 + (wn * 64 + nt * 32 + ml) * H + ks * 16 + g * 8);

    float bias1[2], bias2[2];
#pragma unroll
    for (int nt = 0; nt < 2; ++nt) {
        bias1[nt] = b1[wn * 64 + nt * 32 + ml];
        bias2[nt] = b2[wn * 64 + nt * 32 + ml];
    }

    __syncthreads();

    f32x16 acc[2][2];
#pragma unroll
    for (int mt = 0; mt < 2; ++mt)
#pragma unroll
        for (int nt = 0; nt < 2; ++nt)
#pragma unroll
            for (int i = 0; i < 16; ++i) acc[mt][nt][i] = 0.f;

    // ---- GEMM1 --------------------------------------------------------------
#pragma unroll
    for (int ks = 0; ks < 8; ++ks) {
        bf16x8 afrag[2];
#pragma unroll
        for (int mt = 0; mt < 2; ++mt) {
            int m = wm * 64 + mt * 32 + ml;
            int chunk = (2 * ks + g) ^ (m & 15);
            afrag[mt] = *(const bf16x8*)(&lds[m * H + (chunk << 3)]);
        }
#pragma unroll
        for (int mt = 0; mt < 2; ++mt)
#pragma unroll
            for (int nt = 0; nt < 2; ++nt)
                acc[mt][nt] = __builtin_amdgcn_mfma_f32_32x32x16_bf16(
                    afrag[mt], bfrag[nt][ks], acc[mt][nt], 0, 0, 0);
    }

    __syncthreads();  // all A reads done before T overwrites LDS

    // ---- T = relu(acc + b1) -> LDS ------------------------------------------
#pragma unroll
    for (int mt = 0; mt < 2; ++mt)
#pragma unroll
        for (int nt = 0; nt < 2; ++nt)
#pragma unroll
            for (int reg = 0; reg < 16; ++reg) {
                int rm = wm * 64 + mt * 32 + (reg & 3) + ((reg >> 2) << 3) + 4 * g;
                int cn = wn * 64 + nt * 32 + ml;
                float v = acc[mt][nt][reg] + bias1[nt];
                v = v > 0.f ? v : 0.f;
                lds[rm * H + ((((cn >> 3) ^ (rm & 15))) << 3) + (cn & 7)] = f2bf(v);
            }

    // ---- B2 fragments -------------------------------------------------------
#pragma unroll
    for (int nt = 0; nt < 2; ++nt)
#pragma unroll
        for (int ks = 0; ks < 8; ++ks)
            bfrag[nt][ks] = *(const bf16x8*)(wt2 + (wn * 64 + nt * 32 + ml) * H + ks * 16 + g * 8);

#pragma unroll
    for (int mt = 0; mt < 2; ++mt)
#pragma unroll
        for (int nt = 0; nt < 2; ++nt)
#pragma unroll
            for (int i = 0; i < 16; ++i) acc[mt][nt][i] = 0.f;

    __syncthreads();

    // ---- GEMM2 --------------------------------------------------------------
#pragma unroll
    for (int ks = 0; ks < 8; ++ks) {
        bf16x8 afrag[2];
#pragma unroll
        for (int mt = 0; mt < 2; ++mt) {
            int m = wm * 64 + mt * 32 + ml;
            int chunk = (2 * ks + g) ^ (m & 15);
            afrag[mt] = *(const bf16x8*)(&lds[m * H + (chunk << 3)]);
        }
#pragma unroll
        for (int mt = 0; mt < 2; ++mt)
#pragma unroll
            for (int nt = 0; nt < 2; ++nt)
                acc[mt][nt] = __builtin_amdgcn_mfma_f32_32x32x16_bf16(
                    afrag[mt], bfrag[nt][ks], acc[mt][nt], 0, 0, 0);
    }

    __syncthreads();  // all T reads done before h overwrites LDS

    // ---- h = relu(acc + b2) -> LDS (same swizzle) ---------------------------
#pragma unroll
    for (int mt = 0; mt < 2; ++mt)
#pragma unroll
        for (int nt = 0; nt < 2; ++nt)
#pragma unroll
            for (int reg = 0; reg < 16; ++reg) {
                int rm = wm * 64 + mt * 32 + (reg & 3) + ((reg >> 2) << 3) + 4 * g;
                int cn = wn * 64 + nt * 32 + ml;
                float v = acc[mt][nt][reg] + bias2[nt];
                v = v > 0.f ? v : 0.f;
                lds[rm * H + ((((cn >> 3) ^ (rm & 15))) << 3) + (cn & 7)] = f2bf(v);
            }

    __syncthreads();

    // ---- coalesced residual update: x += h; xbout = bf16(x) -----------------
#pragma unroll
    for (int i = 0; i < 8; ++i) {
        int ch = tid + 256 * i;
        int r = ch >> 4, c = ch & 15;
        int gr = row0 + r;
        if (gr < NN) {
            int4 hv = *(const int4*)(&lds[r * H + ((c ^ (r & 15)) << 3)]);
            float4 x0 = *(const float4*)(x + gr * H + c * 8);
            float4 x1 = *(const float4*)(x + gr * H + c * 8 + 4);
            x0.x += bflo((u32)hv.x); x0.y += bfhi((u32)hv.x);
            x0.z += bflo((u32)hv.y); x0.w += bfhi((u32)hv.y);
            x1.x += bflo((u32)hv.z); x1.y += bfhi((u32)hv.z);
            x1.z += bflo((u32)hv.w); x1.w += bfhi((u32)hv.w);
            *(float4*)(x + gr * H + c * 8) = x0;
            *(float4*)(x + gr * H + c * 8 + 4) = x1;
            int4 xo;
            xo.x = (int)((u32)f2bf(x0.x) | ((u32)f2bf(x0.y) << 16));
            xo.y = (int)((u32)f2bf(x0.z) | ((u32)f2bf(x0.w) << 16));
            xo.z = (int)((u32)f2bf(x1.x) | ((u32)f2bf(x1.y) << 16));
            xo.w = (int)((u32)f2bf(x1.z) | ((u32)f2bf(x1.w) << 16));
            *(int4*)(xbout + gr * H + c * 8) = xo;
        }
    }
}

extern "C" void kernel_launch(void* const* d_in, const int* in_sizes, int n_in,
                              void* d_out, int out_size, void* d_ws, size_t ws_size,
                              hipStream_t stream) {
    const float* x_in = (const float*)d_in[0];
    const int* edges = (const int*)d_in[1];
    const float* W1 = (const float*)d_in[2];
    const float* b1 = (const float*)d_in[3];
    const float* W2 = (const float*)d_in[4];
    const float* b2 = (const float*)d_in[5];
    float* x = (float*)d_out;

    char* ws = (char*)d_ws;
    int* flag = (int*)ws;                        // 4B        @ 0
    int* gcursor = (int*)(ws + 512);             // 784B      @ 512
    int* bbase = (int*)(ws + 2048);              // 784B      @ 2048
    int* offs = (int*)(ws + 4096);               // 400004B   @ 4096
    int* colv = (int*)(ws + 406528);             // 6400000B
    u16* wt = (u16*)(ws + 6809600);              // 262144B
    u16* xb0 = (u16*)(ws + 7072768);             // 25600000B
    u16* xb1 = (u16*)(ws + 32672768);            // 25600000B (end ~58.3MB)
    u32* ebuf = (u32*)xb1;                       // 8.03MB, dead before xb1 used

    detect_kernel<<<1, 256, 0, stream>>>(edges, flag, gcursor);
    part_kernel<<<PB_BLOCKS, 256, 0, stream>>>(edges, flag, gcursor, ebuf);
    bscan_kernel<<<1, 256, 0, stream>>>(gcursor, bbase, offs);
    bfill_kernel<<<NB, 256, 0, stream>>>(ebuf, gcursor, bbase, offs, colv);
    wtconv_kernel<<<131072 / 256, 256, 0, stream>>>(W1, W2, wt);
    xinit_kernel<<<(NN * H / 4) / 256, 256, 0, stream>>>(x_in, x, xb0);

    for (int l = 0; l < 4; ++l) {
        u16* xin_l = (l & 1) ? xb1 : xb0;
        u16* xout_l = (l & 1) ? xb0 : xb1;
        layer_kernel<<<(NN + 127) / 128, 256, 0, stream>>>(
            xin_l, colv, offs,
            wt + (l * 2) * 16384, wt + (l * 2 + 1) * 16384,
            b1 + l * 128, b2 + l * 128, x, xout_l);
    }
}

// Round 6
// 568.282 us; speedup vs baseline: 1.7016x; 1.7016x over previous
//
#include <hip/hip_runtime.h>

typedef unsigned short u16;
typedef unsigned int u32;

constexpr int NN = 100000;   // nodes
constexpr int NE = 1600000;  // edges
constexpr int H = 128;       // hidden

constexpr int NB = 196;      // coarse buckets: b = dst >> 9 (512 nodes/bucket)
constexpr int BCAP = 10240;  // per-bucket capacity (mean 8192, +22 sigma)
constexpr int PB_E = 4096;   // edges per partition block
constexpr int PB_BLOCKS = (NE + PB_E - 1) / PB_E;  // 391

typedef __bf16 bf16x8 __attribute__((ext_vector_type(8)));
typedef float f32x16 __attribute__((ext_vector_type(16)));

__device__ __forceinline__ u16 f2bf(float f) {
    union { float f; u32 u; } cv; cv.f = f;
    u32 r = (cv.u + 0x7fffu + ((cv.u >> 16) & 1u)) >> 16;
    return (u16)r;
}
__device__ __forceinline__ float bflo(u32 u) {
    union { u32 u; float f; } cv; cv.u = u << 16; return cv.f;
}
__device__ __forceinline__ float bfhi(u32 u) {
    union { u32 u; float f; } cv; cv.u = u & 0xffff0000u; return cv.f;
}

// ---- detect int64 vs int32 edge storage -------------------------------------
__global__ void detect_kernel(const int* __restrict__ e, int* __restrict__ flag,
                              int* __restrict__ gcursor) {
    __shared__ int anynz;
    if (threadIdx.x == 0) anynz = 0;
    __syncthreads();
    int local = 0;
    for (int i = threadIdx.x; i < 4096; i += 256)
        if (e[2 * i + 1] != 0) local = 1;
    if (local) atomicOr(&anynz, 1);
    __syncthreads();
    if (threadIdx.x == 0) flag[0] = anynz ? 1 : 2;  // stride in int32 units
    if (threadIdx.x < NB) gcursor[threadIdx.x] = 0;
}

// ---- partition edges into NB dst-buckets (packed src|ldst) -------------------
__global__ __launch_bounds__(256) void part_kernel(const int* __restrict__ e,
                                                   const int* __restrict__ flag,
                                                   int* __restrict__ gcursor,
                                                   u32* __restrict__ ebuf) {
    __shared__ int lcnt[NB];
    __shared__ int gbaseL[NB];
    const int t = threadIdx.x;
    if (t < NB) lcnt[t] = 0;
    __syncthreads();
    const int st = flag[0];
    const int base = blockIdx.x * PB_E;
    u32 pk[16]; int bk[16]; int rk[16];
#pragma unroll
    for (int j = 0; j < 16; ++j) {
        int i = base + j * 256 + t;
        bk[j] = -1;
        if (i < NE) {
            int s = e[st * i];
            int d = e[st * (NE + i)];
            int b = d >> 9;
            pk[j] = (u32)s | ((u32)(d & 511) << 17);
            bk[j] = b;
            rk[j] = atomicAdd(&lcnt[b], 1);
        }
    }
    __syncthreads();
    if (t < NB) gbaseL[t] = atomicAdd(&gcursor[t], lcnt[t]);
    __syncthreads();
#pragma unroll
    for (int j = 0; j < 16; ++j)
        if (bk[j] >= 0)
            ebuf[bk[j] * BCAP + gbaseL[bk[j]] + rk[j]] = pk[j];
}

// ---- exclusive scan of bucket totals ----------------------------------------
__global__ __launch_bounds__(256) void bscan_kernel(const int* __restrict__ gcursor,
                                                    int* __restrict__ bbase,
                                                    int* __restrict__ offs) {
    __shared__ int s[256];
    int t = threadIdx.x;
    int v = (t < NB) ? gcursor[t] : 0;
    s[t] = v;
    __syncthreads();
    for (int off = 1; off < 256; off <<= 1) {
        int u = (t >= off) ? s[t - off] : 0;
        __syncthreads();
        s[t] += u;
        __syncthreads();
    }
    if (t < NB) bbase[t] = s[t] - v;
    if (t == 0) offs[NN] = NE;
}

// ---- per-bucket CSR fill: LDS node counts/scan/cursors, local colv scatter ---
__global__ __launch_bounds__(256) void bfill_kernel(const u32* __restrict__ ebuf,
                                                    const int* __restrict__ gcursor,
                                                    const int* __restrict__ bbase,
                                                    int* __restrict__ offs,
                                                    int* __restrict__ colv) {
    __shared__ int ncnt[512];
    __shared__ int cur[512];
    __shared__ int ps[256];
    const int b = blockIdx.x, t = threadIdx.x;
    const int En = gcursor[b];
    const int bb = bbase[b];
    ncnt[t] = 0; ncnt[t + 256] = 0;
    __syncthreads();
    const u32* eb = ebuf + b * BCAP;
    for (int i = t; i < En; i += 256)
        atomicAdd(&ncnt[eb[i] >> 17], 1);
    __syncthreads();
    int s2 = ncnt[2 * t] + ncnt[2 * t + 1];
    ps[t] = s2;
    __syncthreads();
    for (int off = 1; off < 256; off <<= 1) {
        int u = (t >= off) ? ps[t - off] : 0;
        __syncthreads();
        ps[t] += u;
        __syncthreads();
    }
    int e0 = ps[t] - s2;  // exclusive
    cur[2 * t] = e0;
    cur[2 * t + 1] = e0 + ncnt[2 * t];
    __syncthreads();
    const int n0 = b * 512;
    for (int i = t; i < 512; i += 256)
        if (n0 + i < NN) offs[n0 + i] = bb + cur[i];
    __syncthreads();  // offs reads of cur[] complete before pass2 mutates
    for (int i = t; i < En; i += 256) {
        u32 p = eb[i];
        int pos = atomicAdd(&cur[p >> 17], 1);
        colv[bb + pos] = (int)(p & 0x1FFFFu);
    }
}

// ---- transpose+convert weights: Wt[l*2+s][n][k] = W[l][k][n] (bf16) ---------
__global__ void wtconv_kernel(const float* __restrict__ W1,
                              const float* __restrict__ W2,
                              u16* __restrict__ wt) {
    int t = blockIdx.x * 256 + threadIdx.x;  // 131072 threads
    int w = t >> 14;      // 0..7 = l*2+s
    int r = t & 16383;
    int k = r >> 7, n = r & 127;  // n fastest -> coalesced reads
    int l = w >> 1, s = w & 1;
    const float* src = (s == 0 ? W1 : W2) + l * 16384;
    wt[w * 16384 + n * 128 + k] = f2bf(src[k * 128 + n]);
}

// ---- x init: copy fp32 x -> d_out, make bf16 shadow -------------------------
__global__ void xinit_kernel(const float* __restrict__ xin,
                             float* __restrict__ x, u16* __restrict__ xb) {
    int i = blockIdx.x * 256 + threadIdx.x;  // NN*H/4 threads
    float4 v = ((const float4*)xin)[i];
    ((float4*)x)[i] = v;
    uint2 p;
    p.x = (u32)f2bf(v.x) | ((u32)f2bf(v.y) << 16);
    p.y = (u32)f2bf(v.z) | ((u32)f2bf(v.w) << 16);
    ((uint2*)xb)[i] = p;
}

// ---- aggregation: out[i] = bf16( sum_{j in N(i)} xb[j] + xb[i] ) ------------
// One wave per node: maximal TLP to hide L2/L3 gather latency (R4 lesson:
// fusing this into the GEMM kernel collapses TLP 32x and regresses badly).
__global__ __launch_bounds__(256) void agg_kernel(const u16* __restrict__ xb,
                                                  const int* __restrict__ colv,
                                                  const int* __restrict__ offs,
                                                  u16* __restrict__ out) {
    const int lane = threadIdx.x & 63;
    const int node = blockIdx.x * 4 + (threadIdx.x >> 6);
    if (node >= NN) return;
    const int rs = offs[node], re = offs[node + 1];
    u32 su = *(const u32*)(xb + node * H + lane * 2);
    float a0 = bflo(su), a1 = bfhi(su);
    for (int base = rs; base < re; base += 64) {
        int cnt = re - base; if (cnt > 64) cnt = 64;
        int c = 0;
        if (lane < cnt) c = colv[base + lane];
        int j = 0;
        for (; j + 4 <= cnt; j += 4) {
            int s0 = __shfl(c, j), s1 = __shfl(c, j + 1);
            int s2 = __shfl(c, j + 2), s3 = __shfl(c, j + 3);
            u32 u0 = *(const u32*)(xb + s0 * H + lane * 2);
            u32 u1 = *(const u32*)(xb + s1 * H + lane * 2);
            u32 u2 = *(const u32*)(xb + s2 * H + lane * 2);
            u32 u3 = *(const u32*)(xb + s3 * H + lane * 2);
            a0 += bflo(u0) + bflo(u1) + bflo(u2) + bflo(u3);
            a1 += bfhi(u0) + bfhi(u1) + bfhi(u2) + bfhi(u3);
        }
        for (; j < cnt; ++j) {
            int s = __shfl(c, j);
            u32 u = *(const u32*)(xb + s * H + lane * 2);
            a0 += bflo(u); a1 += bfhi(u);
        }
    }
    u32 o = (u32)f2bf(a0) | ((u32)f2bf(a1) << 16);
    *(u32*)(out + node * H + lane * 2) = o;
}

// ---- fused MLP: x += relu( relu(agg@W1+b1)@W2 + b2 ); xb = bf16(x) ----------
// Coalesced LDS epilogue (validated in R5): h -> swizzled LDS -> float4 x-update.
__global__ __launch_bounds__(256) void mlp_kernel(const u16* __restrict__ agg,
                                                  const u16* __restrict__ wt1,
                                                  const u16* __restrict__ wt2,
                                                  const float* __restrict__ b1,
                                                  const float* __restrict__ b2,
                                                  float* __restrict__ x,
                                                  u16* __restrict__ xb) {
    __shared__ u16 lds[128 * 128];  // 32KB, XOR-swizzled 16B chunks
    const int tid = threadIdx.x;
    const int wave = tid >> 6, lane = tid & 63;
    const int wm = wave >> 1, wn = wave & 1;  // 2x2 wave grid, 64x64 per wave
    const int ml = lane & 31, g = lane >> 5;
    const int row0 = blockIdx.x * 128;

    // stage A tile (swizzle: chunk c of row r stored at chunk c^(r&15))
#pragma unroll
    for (int i = 0; i < 8; ++i) {
        int ch = tid + 256 * i;
        int r = ch >> 4, c = ch & 15;
        int4 v = make_int4(0, 0, 0, 0);
        int gr = row0 + r;
        if (gr < NN) v = *(const int4*)(agg + gr * H + c * 8);
        *(int4*)(&lds[r * H + ((c ^ (r & 15)) << 3)]) = v;
    }

    // B1 fragments from global (L2-resident): B[k][n], n=ml, k=(g*8..)+j
    bf16x8 bfrag[2][8];
#pragma unroll
    for (int nt = 0; nt < 2; ++nt)
#pragma unroll
        for (int ks = 0; ks < 8; ++ks)
            bfrag[nt][ks] = *(const bf16x8*)(wt1 + (wn * 64 + nt * 32 + ml) * H + ks * 16 + g * 8);

    float bias1[2], bias2[2];
#pragma unroll
    for (int nt = 0; nt < 2; ++nt) {
        bias1[nt] = b1[wn * 64 + nt * 32 + ml];
        bias2[nt] = b2[wn * 64 + nt * 32 + ml];
    }

    __syncthreads();

    f32x16 acc[2][2];
#pragma unroll
    for (int mt = 0; mt < 2; ++mt)
#pragma unroll
        for (int nt = 0; nt < 2; ++nt)
#pragma unroll
            for (int i = 0; i < 16; ++i) acc[mt][nt][i] = 0.f;

    // GEMM1
#pragma unroll
    for (int ks = 0; ks < 8; ++ks) {
        bf16x8 afrag[2];
#pragma unroll
        for (int mt = 0; mt < 2; ++mt) {
            int m = wm * 64 + mt * 32 + ml;
            int chunk = (2 * ks + g) ^ (m & 15);
            afrag[mt] = *(const bf16x8*)(&lds[m * H + (chunk << 3)]);
        }
#pragma unroll
        for (int mt = 0; mt < 2; ++mt)
#pragma unroll
            for (int nt = 0; nt < 2; ++nt)
                acc[mt][nt] = __builtin_amdgcn_mfma_f32_32x32x16_bf16(
                    afrag[mt], bfrag[nt][ks], acc[mt][nt], 0, 0, 0);
    }

    __syncthreads();  // all A reads done before T overwrites LDS

    // T = relu(acc + b1) -> LDS (C-layout -> row-major[m][k], swizzled)
#pragma unroll
    for (int mt = 0; mt < 2; ++mt)
#pragma unroll
        for (int nt = 0; nt < 2; ++nt)
#pragma unroll
            for (int reg = 0; reg < 16; ++reg) {
                int rm = wm * 64 + mt * 32 + (reg & 3) + ((reg >> 2) << 3) + 4 * g;
                int cn = wn * 64 + nt * 32 + ml;
                float v = acc[mt][nt][reg] + bias1[nt];
                v = v > 0.f ? v : 0.f;
                lds[rm * H + ((((cn >> 3) ^ (rm & 15))) << 3) + (cn & 7)] = f2bf(v);
            }

    // B2 fragments
#pragma unroll
    for (int nt = 0; nt < 2; ++nt)
#pragma unroll
        for (int ks = 0; ks < 8; ++ks)
            bfrag[nt][ks] = *(const bf16x8*)(wt2 + (wn * 64 + nt * 32 + ml) * H + ks * 16 + g * 8);

#pragma unroll
    for (int mt = 0; mt < 2; ++mt)
#pragma unroll
        for (int nt = 0; nt < 2; ++nt)
#pragma unroll
            for (int i = 0; i < 16; ++i) acc[mt][nt][i] = 0.f;

    __syncthreads();

    // GEMM2
#pragma unroll
    for (int ks = 0; ks < 8; ++ks) {
        bf16x8 afrag[2];
#pragma unroll
        for (int mt = 0; mt < 2; ++mt) {
            int m = wm * 64 + mt * 32 + ml;
            int chunk = (2 * ks + g) ^ (m & 15);
            afrag[mt] = *(const bf16x8*)(&lds[m * H + (chunk << 3)]);
        }
#pragma unroll
        for (int mt = 0; mt < 2; ++mt)
#pragma unroll
            for (int nt = 0; nt < 2; ++nt)
                acc[mt][nt] = __builtin_amdgcn_mfma_f32_32x32x16_bf16(
                    afrag[mt], bfrag[nt][ks], acc[mt][nt], 0, 0, 0);
    }

    __syncthreads();  // all T reads done before h overwrites LDS

    // h = relu(acc + b2) -> LDS (same swizzle)
#pragma unroll
    for (int mt = 0; mt < 2; ++mt)
#pragma unroll
        for (int nt = 0; nt < 2; ++nt)
#pragma unroll
            for (int reg = 0; reg < 16; ++reg) {
                int rm = wm * 64 + mt * 32 + (reg & 3) + ((reg >> 2) << 3) + 4 * g;
                int cn = wn * 64 + nt * 32 + ml;
                float v = acc[mt][nt][reg] + bias2[nt];
                v = v > 0.f ? v : 0.f;
                lds[rm * H + ((((cn >> 3) ^ (rm & 15))) << 3) + (cn & 7)] = f2bf(v);
            }

    __syncthreads();

    // coalesced residual update: x += h; xb = bf16(x)
#pragma unroll
    for (int i = 0; i < 8; ++i) {
        int ch = tid + 256 * i;
        int r = ch >> 4, c = ch & 15;
        int gr = row0 + r;
        if (gr < NN) {
            int4 hv = *(const int4*)(&lds[r * H + ((c ^ (r & 15)) << 3)]);
            float4 x0 = *(const float4*)(x + gr * H + c * 8);
            float4 x1 = *(const float4*)(x + gr * H + c * 8 + 4);
            x0.x += bflo((u32)hv.x); x0.y += bfhi((u32)hv.x);
            x0.z += bflo((u32)hv.y); x0.w += bfhi((u32)hv.y);
            x1.x += bflo((u32)hv.z); x1.y += bfhi((u32)hv.z);
            x1.z += bflo((u32)hv.w); x1.w += bfhi((u32)hv.w);
            *(float4*)(x + gr * H + c * 8) = x0;
            *(float4*)(x + gr * H + c * 8 + 4) = x1;
            int4 xo;
            xo.x = (int)((u32)f2bf(x0.x) | ((u32)f2bf(x0.y) << 16));
            xo.y = (int)((u32)f2bf(x0.z) | ((u32)f2bf(x0.w) << 16));
            xo.z = (int)((u32)f2bf(x1.x) | ((u32)f2bf(x1.y) << 16));
            xo.w = (int)((u32)f2bf(x1.z) | ((u32)f2bf(x1.w) << 16));
            *(int4*)(xb + gr * H + c * 8) = xo;
        }
    }
}

extern "C" void kernel_launch(void* const* d_in, const int* in_sizes, int n_in,
                              void* d_out, int out_size, void* d_ws, size_t ws_size,
                              hipStream_t stream) {
    const float* x_in = (const float*)d_in[0];
    const int* edges = (const int*)d_in[1];
    const float* W1 = (const float*)d_in[2];
    const float* b1 = (const float*)d_in[3];
    const float* W2 = (const float*)d_in[4];
    const float* b2 = (const float*)d_in[5];
    float* x = (float*)d_out;

    char* ws = (char*)d_ws;
    int* flag = (int*)ws;                        // 4B        @ 0
    int* gcursor = (int*)(ws + 512);             // 784B      @ 512
    int* bbase = (int*)(ws + 2048);              // 784B      @ 2048
    int* offs = (int*)(ws + 4096);               // 400004B   @ 4096
    int* colv = (int*)(ws + 406528);             // 6400000B
    u16* wt = (u16*)(ws + 6809600);              // 262144B
    u16* xb = (u16*)(ws + 7072768);              // 25600000B
    u16* aggout = (u16*)(ws + 32672768);         // 25600000B (end ~58.3MB)
    u32* ebuf = (u32*)aggout;                    // 8.03MB, dead before aggout used

    detect_kernel<<<1, 256, 0, stream>>>(edges, flag, gcursor);
    part_kernel<<<PB_BLOCKS, 256, 0, stream>>>(edges, flag, gcursor, ebuf);
    bscan_kernel<<<1, 256, 0, stream>>>(gcursor, bbase, offs);
    bfill_kernel<<<NB, 256, 0, stream>>>(ebuf, gcursor, bbase, offs, colv);
    wtconv_kernel<<<131072 / 256, 256, 0, stream>>>(W1, W2, wt);
    xinit_kernel<<<(NN * H / 4) / 256, 256, 0, stream>>>(x_in, x, xb);

    for (int l = 0; l < 4; ++l) {
        agg_kernel<<<NN / 4, 256, 0, stream>>>(xb, colv, offs, aggout);
        mlp_kernel<<<(NN + 127) / 128, 256, 0, stream>>>(
            aggout, wt + (l * 2) * 16384, wt + (l * 2 + 1) * 16384,
            b1 + l * 128, b2 + l * 128, x, xb);
    }
}

// Round 7
// 562.715 us; speedup vs baseline: 1.7185x; 1.0099x over previous
//
#include <hip/hip_runtime.h>

typedef unsigned short u16;
typedef unsigned int u32;

constexpr int NN = 100000;   // nodes
constexpr int NE = 1600000;  // edges
constexpr int H = 128;       // hidden

constexpr int NB = 196;      // coarse buckets: b = dst >> 9 (512 nodes/bucket)
constexpr int BCAP = 10240;  // per-bucket capacity (mean 8192, +22 sigma)
constexpr int PB_E = 4096;   // edges per partition block
constexpr int PB_BLOCKS = (NE + PB_E - 1) / PB_E;  // 391

typedef __bf16 bf16x8 __attribute__((ext_vector_type(8)));
typedef float f32x16 __attribute__((ext_vector_type(16)));

__device__ __forceinline__ u16 f2bf(float f) {
    union { float f; u32 u; } cv; cv.f = f;
    u32 r = (cv.u + 0x7fffu + ((cv.u >> 16) & 1u)) >> 16;
    return (u16)r;
}
__device__ __forceinline__ float bflo(u32 u) {
    union { u32 u; float f; } cv; cv.u = u << 16; return cv.f;
}
__device__ __forceinline__ float bfhi(u32 u) {
    union { u32 u; float f; } cv; cv.u = u & 0xffff0000u; return cv.f;
}

// ---- detect int64 vs int32 edge storage -------------------------------------
__global__ void detect_kernel(const int* __restrict__ e, int* __restrict__ flag,
                              int* __restrict__ gcursor) {
    __shared__ int anynz;
    if (threadIdx.x == 0) anynz = 0;
    __syncthreads();
    int local = 0;
    for (int i = threadIdx.x; i < 4096; i += 256)
        if (e[2 * i + 1] != 0) local = 1;
    if (local) atomicOr(&anynz, 1);
    __syncthreads();
    if (threadIdx.x == 0) flag[0] = anynz ? 1 : 2;  // stride in int32 units
    if (threadIdx.x < NB) gcursor[threadIdx.x] = 0;
}

// ---- partition edges into NB dst-buckets (packed src|ldst) -------------------
__global__ __launch_bounds__(256) void part_kernel(const int* __restrict__ e,
                                                   const int* __restrict__ flag,
                                                   int* __restrict__ gcursor,
                                                   u32* __restrict__ ebuf) {
    __shared__ int lcnt[NB];
    __shared__ int gbaseL[NB];
    const int t = threadIdx.x;
    if (t < NB) lcnt[t] = 0;
    __syncthreads();
    const int st = flag[0];
    const int base = blockIdx.x * PB_E;
    u32 pk[16]; int bk[16]; int rk[16];
#pragma unroll
    for (int j = 0; j < 16; ++j) {
        int i = base + j * 256 + t;
        bk[j] = -1;
        if (i < NE) {
            int s = e[st * i];
            int d = e[st * (NE + i)];
            int b = d >> 9;
            pk[j] = (u32)s | ((u32)(d & 511) << 17);
            bk[j] = b;
            rk[j] = atomicAdd(&lcnt[b], 1);
        }
    }
    __syncthreads();
    if (t < NB) gbaseL[t] = atomicAdd(&gcursor[t], lcnt[t]);
    __syncthreads();
#pragma unroll
    for (int j = 0; j < 16; ++j)
        if (bk[j] >= 0)
            ebuf[bk[j] * BCAP + gbaseL[bk[j]] + rk[j]] = pk[j];
}

// ---- exclusive scan of bucket totals ----------------------------------------
__global__ __launch_bounds__(256) void bscan_kernel(const int* __restrict__ gcursor,
                                                    int* __restrict__ bbase,
                                                    int* __restrict__ offs) {
    __shared__ int s[256];
    int t = threadIdx.x;
    int v = (t < NB) ? gcursor[t] : 0;
    s[t] = v;
    __syncthreads();
    for (int off = 1; off < 256; off <<= 1) {
        int u = (t >= off) ? s[t - off] : 0;
        __syncthreads();
        s[t] += u;
        __syncthreads();
    }
    if (t < NB) bbase[t] = s[t] - v;
    if (t == 0) offs[NN] = NE;
}

// ---- per-bucket CSR fill: LDS node counts/scan/cursors, local colv scatter ---
__global__ __launch_bounds__(256) void bfill_kernel(const u32* __restrict__ ebuf,
                                                    const int* __restrict__ gcursor,
                                                    const int* __restrict__ bbase,
                                                    int* __restrict__ offs,
                                                    int* __restrict__ colv) {
    __shared__ int ncnt[512];
    __shared__ int cur[512];
    __shared__ int ps[256];
    const int b = blockIdx.x, t = threadIdx.x;
    const int En = gcursor[b];
    const int bb = bbase[b];
    ncnt[t] = 0; ncnt[t + 256] = 0;
    __syncthreads();
    const u32* eb = ebuf + b * BCAP;
    for (int i = t; i < En; i += 256)
        atomicAdd(&ncnt[eb[i] >> 17], 1);
    __syncthreads();
    int s2 = ncnt[2 * t] + ncnt[2 * t + 1];
    ps[t] = s2;
    __syncthreads();
    for (int off = 1; off < 256; off <<= 1) {
        int u = (t >= off) ? ps[t - off] : 0;
        __syncthreads();
        ps[t] += u;
        __syncthreads();
    }
    int e0 = ps[t] - s2;  // exclusive
    cur[2 * t] = e0;
    cur[2 * t + 1] = e0 + ncnt[2 * t];
    __syncthreads();
    const int n0 = b * 512;
    for (int i = t; i < 512; i += 256)
        if (n0 + i < NN) offs[n0 + i] = bb + cur[i];
    __syncthreads();  // offs reads of cur[] complete before pass2 mutates
    for (int i = t; i < En; i += 256) {
        u32 p = eb[i];
        int pos = atomicAdd(&cur[p >> 17], 1);
        colv[bb + pos] = (int)(p & 0x1FFFFu);
    }
}

// ---- transpose+convert weights: Wt[l*2+s][n][k] = W[l][k][n] (bf16) ---------
__global__ void wtconv_kernel(const float* __restrict__ W1,
                              const float* __restrict__ W2,
                              u16* __restrict__ wt) {
    int t = blockIdx.x * 256 + threadIdx.x;  // 131072 threads
    int w = t >> 14;      // 0..7 = l*2+s
    int r = t & 16383;
    int k = r >> 7, n = r & 127;  // n fastest -> coalesced reads
    int l = w >> 1, s = w & 1;
    const float* src = (s == 0 ? W1 : W2) + l * 16384;
    wt[w * 16384 + n * 128 + k] = f2bf(src[k * 128 + n]);
}

// ---- x init: copy fp32 x -> d_out, make bf16 shadow -------------------------
__global__ void xinit_kernel(const float* __restrict__ xin,
                             float* __restrict__ x, u16* __restrict__ xb) {
    int i = blockIdx.x * 256 + threadIdx.x;  // NN*H/4 threads
    float4 v = ((const float4*)xin)[i];
    ((float4*)x)[i] = v;
    uint2 p;
    p.x = (u32)f2bf(v.x) | ((u32)f2bf(v.y) << 16);
    p.y = (u32)f2bf(v.z) | ((u32)f2bf(v.w) << 16);
    ((uint2*)xb)[i] = p;
}

// ---- aggregation: out[i] = bf16( sum_{j in N(i)} xb[j] + xb[i] ) ------------
// One wave per node (TLP for latency hiding — R4 lesson). Neighbor indices are
// wave-uniform: readfirstlane forces them into SGPRs so the gather is
// global_load_dword v, v_off(const), s[rowbase] — no ds_bpermute, no per-edge
// VALU address math; 8-deep unroll keeps 8x256B in flight per wave.
__global__ __launch_bounds__(256) void agg_kernel(const u16* __restrict__ xb,
                                                  const int* __restrict__ colv,
                                                  const int* __restrict__ offs,
                                                  u16* __restrict__ out) {
    const int lane = threadIdx.x & 63;
    const int node = __builtin_amdgcn_readfirstlane(blockIdx.x * 4 + (threadIdx.x >> 6));
    const int rs = __builtin_amdgcn_readfirstlane(offs[node]);
    const int re = __builtin_amdgcn_readfirstlane(offs[node + 1]);
    u32 su = *(const u32*)(xb + node * H + lane * 2);
    float a0 = bflo(su), a1 = bfhi(su);
    int j = rs;
    for (; j + 8 <= re; j += 8) {
        u32 uu[8];
#pragma unroll
        for (int q = 0; q < 8; ++q) {
            int s = __builtin_amdgcn_readfirstlane(colv[j + q]);
            uu[q] = *(const u32*)(xb + s * H + lane * 2);
        }
#pragma unroll
        for (int q = 0; q < 8; ++q) { a0 += bflo(uu[q]); a1 += bfhi(uu[q]); }
    }
    for (; j < re; ++j) {
        int s = __builtin_amdgcn_readfirstlane(colv[j]);
        u32 u = *(const u32*)(xb + s * H + lane * 2);
        a0 += bflo(u); a1 += bfhi(u);
    }
    u32 o = (u32)f2bf(a0) | ((u32)f2bf(a1) << 16);
    *(u32*)(out + node * H + lane * 2) = o;
}

// ---- fused MLP: x += relu( relu(agg@W1+b1)@W2 + b2 ); xb = bf16(x) ----------
// Coalesced LDS epilogue (validated in R5): h -> swizzled LDS -> float4 x-update.
__global__ __launch_bounds__(256) void mlp_kernel(const u16* __restrict__ agg,
                                                  const u16* __restrict__ wt1,
                                                  const u16* __restrict__ wt2,
                                                  const float* __restrict__ b1,
                                                  const float* __restrict__ b2,
                                                  float* __restrict__ x,
                                                  u16* __restrict__ xb) {
    __shared__ u16 lds[128 * 128];  // 32KB, XOR-swizzled 16B chunks
    const int tid = threadIdx.x;
    const int wave = tid >> 6, lane = tid & 63;
    const int wm = wave >> 1, wn = wave & 1;  // 2x2 wave grid, 64x64 per wave
    const int ml = lane & 31, g = lane >> 5;
    const int row0 = blockIdx.x * 128;

    // stage A tile (swizzle: chunk c of row r stored at chunk c^(r&15))
#pragma unroll
    for (int i = 0; i < 8; ++i) {
        int ch = tid + 256 * i;
        int r = ch >> 4, c = ch & 15;
        int4 v = make_int4(0, 0, 0, 0);
        int gr = row0 + r;
        if (gr < NN) v = *(const int4*)(agg + gr * H + c * 8);
        *(int4*)(&lds[r * H + ((c ^ (r & 15)) << 3)]) = v;
    }

    // B1 fragments from global (L2-resident): B[k][n], n=ml, k=(g*8..)+j
    bf16x8 bfrag[2][8];
#pragma unroll
    for (int nt = 0; nt < 2; ++nt)
#pragma unroll
        for (int ks = 0; ks < 8; ++ks)
            bfrag[nt][ks] = *(const bf16x8*)(wt1 + (wn * 64 + nt * 32 + ml) * H + ks * 16 + g * 8);

    float bias1[2], bias2[2];
#pragma unroll
    for (int nt = 0; nt < 2; ++nt) {
        bias1[nt] = b1[wn * 64 + nt * 32 + ml];
        bias2[nt] = b2[wn * 64 + nt * 32 + ml];
    }

    __syncthreads();

    f32x16 acc[2][2];
#pragma unroll
    for (int mt = 0; mt < 2; ++mt)
#pragma unroll
        for (int nt = 0; nt < 2; ++nt)
#pragma unroll
            for (int i = 0; i < 16; ++i) acc[mt][nt][i] = 0.f;

    // GEMM1
#pragma unroll
    for (int ks = 0; ks < 8; ++ks) {
        bf16x8 afrag[2];
#pragma unroll
        for (int mt = 0; mt < 2; ++mt) {
            int m = wm * 64 + mt * 32 + ml;
            int chunk = (2 * ks + g) ^ (m & 15);
            afrag[mt] = *(const bf16x8*)(&lds[m * H + (chunk << 3)]);
        }
#pragma unroll
        for (int mt = 0; mt < 2; ++mt)
#pragma unroll
            for (int nt = 0; nt < 2; ++nt)
                acc[mt][nt] = __builtin_amdgcn_mfma_f32_32x32x16_bf16(
                    afrag[mt], bfrag[nt][ks], acc[mt][nt], 0, 0, 0);
    }

    __syncthreads();  // all A reads done before T overwrites LDS

    // T = relu(acc + b1) -> LDS (C-layout -> row-major[m][k], swizzled)
#pragma unroll
    for (int mt = 0; mt < 2; ++mt)
#pragma unroll
        for (int nt = 0; nt < 2; ++nt)
#pragma unroll
            for (int reg = 0; reg < 16; ++reg) {
                int rm = wm * 64 + mt * 32 + (reg & 3) + ((reg >> 2) << 3) + 4 * g;
                int cn = wn * 64 + nt * 32 + ml;
                float v = acc[mt][nt][reg] + bias1[nt];
                v = v > 0.f ? v : 0.f;
                lds[rm * H + ((((cn >> 3) ^ (rm & 15))) << 3) + (cn & 7)] = f2bf(v);
            }

    // B2 fragments
#pragma unroll
    for (int nt = 0; nt < 2; ++nt)
#pragma unroll
        for (int ks = 0; ks < 8; ++ks)
            bfrag[nt][ks] = *(const bf16x8*)(wt2 + (wn * 64 + nt * 32 + ml) * H + ks * 16 + g * 8);

#pragma unroll
    for (int mt = 0; mt < 2; ++mt)
#pragma unroll
        for (int nt = 0; nt < 2; ++nt)
#pragma unroll
            for (int i = 0; i < 16; ++i) acc[mt][nt][i] = 0.f;

    __syncthreads();

    // GEMM2
#pragma unroll
    for (int ks = 0; ks < 8; ++ks) {
        bf16x8 afrag[2];
#pragma unroll
        for (int mt = 0; mt < 2; ++mt) {
            int m = wm * 64 + mt * 32 + ml;
            int chunk = (2 * ks + g) ^ (m & 15);
            afrag[mt] = *(const bf16x8*)(&lds[m * H + (chunk << 3)]);
        }
#pragma unroll
        for (int mt = 0; mt < 2; ++mt)
#pragma unroll
            for (int nt = 0; nt < 2; ++nt)
                acc[mt][nt] = __builtin_amdgcn_mfma_f32_32x32x16_bf16(
                    afrag[mt], bfrag[nt][ks], acc[mt][nt], 0, 0, 0);
    }

    __syncthreads();  // all T reads done before h overwrites LDS

    // h = relu(acc + b2) -> LDS (same swizzle)
#pragma unroll
    for (int mt = 0; mt < 2; ++mt)
#pragma unroll
        for (int nt = 0; nt < 2; ++nt)
#pragma unroll
            for (int reg = 0; reg < 16; ++reg) {
                int rm = wm * 64 + mt * 32 + (reg & 3) + ((reg >> 2) << 3) + 4 * g;
                int cn = wn * 64 + nt * 32 + ml;
                float v = acc[mt][nt][reg] + bias2[nt];
                v = v > 0.f ? v : 0.f;
                lds[rm * H + ((((cn >> 3) ^ (rm & 15))) << 3) + (cn & 7)] = f2bf(v);
            }

    __syncthreads();

    // coalesced residual update: x += h; xb = bf16(x)
#pragma unroll
    for (int i = 0; i < 8; ++i) {
        int ch = tid + 256 * i;
        int r = ch >> 4, c = ch & 15;
        int gr = row0 + r;
        if (gr < NN) {
            int4 hv = *(const int4*)(&lds[r * H + ((c ^ (r & 15)) << 3)]);
            float4 x0 = *(const float4*)(x + gr * H + c * 8);
            float4 x1 = *(const float4*)(x + gr * H + c * 8 + 4);
            x0.x += bflo((u32)hv.x); x0.y += bfhi((u32)hv.x);
            x0.z += bflo((u32)hv.y); x0.w += bfhi((u32)hv.y);
            x1.x += bflo((u32)hv.z); x1.y += bfhi((u32)hv.z);
            x1.z += bflo((u32)hv.w); x1.w += bfhi((u32)hv.w);
            *(float4*)(x + gr * H + c * 8) = x0;
            *(float4*)(x + gr * H + c * 8 + 4) = x1;
            int4 xo;
            xo.x = (int)((u32)f2bf(x0.x) | ((u32)f2bf(x0.y) << 16));
            xo.y = (int)((u32)f2bf(x0.z) | ((u32)f2bf(x0.w) << 16));
            xo.z = (int)((u32)f2bf(x1.x) | ((u32)f2bf(x1.y) << 16));
            xo.w = (int)((u32)f2bf(x1.z) | ((u32)f2bf(x1.w) << 16));
            *(int4*)(xb + gr * H + c * 8) = xo;
        }
    }
}

extern "C" void kernel_launch(void* const* d_in, const int* in_sizes, int n_in,
                              void* d_out, int out_size, void* d_ws, size_t ws_size,
                              hipStream_t stream) {
    const float* x_in = (const float*)d_in[0];
    const int* edges = (const int*)d_in[1];
    const float* W1 = (const float*)d_in[2];
    const float* b1 = (const float*)d_in[3];
    const float* W2 = (const float*)d_in[4];
    const float* b2 = (const float*)d_in[5];
    float* x = (float*)d_out;

    char* ws = (char*)d_ws;
    int* flag = (int*)ws;                        // 4B        @ 0
    int* gcursor = (int*)(ws + 512);             // 784B      @ 512
    int* bbase = (int*)(ws + 2048);              // 784B      @ 2048
    int* offs = (int*)(ws + 4096);               // 400004B   @ 4096
    int* colv = (int*)(ws + 406528);             // 6400000B
    u16* wt = (u16*)(ws + 6809600);              // 262144B
    u16* xb = (u16*)(ws + 7072768);              // 25600000B
    u16* aggout = (u16*)(ws + 32672768);         // 25600000B (end ~58.3MB)
    u32* ebuf = (u32*)aggout;                    // 8.03MB, dead before aggout used

    detect_kernel<<<1, 256, 0, stream>>>(edges, flag, gcursor);
    part_kernel<<<PB_BLOCKS, 256, 0, stream>>>(edges, flag, gcursor, ebuf);
    bscan_kernel<<<1, 256, 0, stream>>>(gcursor, bbase, offs);
    bfill_kernel<<<NB, 256, 0, stream>>>(ebuf, gcursor, bbase, offs, colv);
    wtconv_kernel<<<131072 / 256, 256, 0, stream>>>(W1, W2, wt);
    xinit_kernel<<<(NN * H / 4) / 256, 256, 0, stream>>>(x_in, x, xb);

    for (int l = 0; l < 4; ++l) {
        agg_kernel<<<NN / 4, 256, 0, stream>>>(xb, colv, offs, aggout);
        mlp_kernel<<<(NN + 127) / 128, 256, 0, stream>>>(
            aggout, wt + (l * 2) * 16384, wt + (l * 2 + 1) * 16384,
            b1 + l * 128, b2 + l * 128, x, xb);
    }
}